// Round 5
// baseline (199.741 us; speedup 1.0000x reference)
//
#include <hip/hip_runtime.h>

// ImageLRU as one GEMM: y[r,:] = W @ x[r,:], W (1024x1024, block-lower-tri)
// built on device from (Lam,B,C,D). R5:
//  - X→bf16 conversion FUSED into the GEMM A-stage (reg-staged: global fp32
//    load early, cvt + ds_write late) — split_x kernel eliminated.
//  - W staged via global_load_lds(16B), tiled ws layout == LDS image.
//  - 2-term precision: y = Xh*(Wh + Wl), double-buffered LDS, 1 barrier/chunk.
//  - mt-major block order: the 8 N-blocks of an M-tile are co-resident, so
//    fp32 X re-reads hit L3/L2 instead of HBM.

namespace {

typedef __attribute__((ext_vector_type(8))) short short8v;
typedef __attribute__((ext_vector_type(4))) float f32x4;

__device__ inline unsigned short f2bf_rne(float f) {
    unsigned u = __builtin_bit_cast(unsigned, f);
    u += 0x7fffu + ((u >> 16) & 1u);
    return (unsigned short)(u >> 16);
}
__device__ inline float bf2f(unsigned short h) {
    unsigned u = ((unsigned)h) << 16;
    return __builtin_bit_cast(float, u);
}

__device__ inline void gld_lds16(const unsigned short* g, unsigned short* l) {
    __builtin_amdgcn_global_load_lds(
        (const __attribute__((address_space(1))) unsigned int*)g,
        (__attribute__((address_space(3))) unsigned int*)l, 16, 0, 0);
}

// Tiled layout for a [128 rows][32 k] bf16 tile: elem (row,k) at
//   tile_base + ((k>>3)<<10) + (row<<3) + (k&7)   (ushort units, 4096/tile)

// ---------------- prep: build Wh/Wl in tiled layout ----------------
__global__ __launch_bounds__(256) void build_w_kernel(
    const float* __restrict__ Lre, const float* __restrict__ Lim,
    const float* __restrict__ Bre, const float* __restrict__ Bim,
    const float* __restrict__ Cre, const float* __restrict__ Cim,
    const float* __restrict__ Dm,
    unsigned short* __restrict__ Wh, unsigned short* __restrict__ Wl)
{
    const int i = blockIdx.x >> 6, j = blockIdx.x & 63;
    const int t = threadIdx.x, k = t >> 4, l = t & 15;

    const int n_g = i * 16 + k;        // W row (n dim)
    const int k_g = j * 16 + l;        // W col (k dim)
    const size_t widx = (((size_t)((n_g >> 7) * 32 + (k_g >> 5))) << 12)
                      + (((k_g >> 3) & 3) << 10) + ((n_g & 127) << 3) + (k_g & 7);

    if (j > i) { Wh[widx] = 0; Wl[widx] = 0; return; }

    __shared__ float2 Bs[16][16];
    __shared__ float2 M[16][16];
    Bs[k][l] = make_float2(Bre[t], Bim[t]);
    M[k][l]  = make_float2(k == l ? 1.f : 0.f, 0.f);
    const int delta = i - j;
    __syncthreads();

    #pragma unroll
    for (int d = 0; d < 6; ++d) {
        const int s = 1 << d;
        if (delta & s) {
            const float lr = Lre[k], li = Lim[k];
            const float2 m0 = M[k][l];
            M[k][l] = make_float2(lr * m0.x - li * m0.y, lr * m0.y + li * m0.x);
            __syncthreads();
        } else if (j + (delta & (s - 1)) >= s) {
            float2 acc = make_float2(0.f, 0.f);
            #pragma unroll
            for (int m = 0; m < 16; ++m) {
                const float2 b = Bs[k][m], v = M[m][l];
                acc.x += b.x * v.x - b.y * v.y;
                acc.y += b.x * v.y + b.y * v.x;
            }
            __syncthreads();
            M[k][l] = acc;
            __syncthreads();
        }
    }

    float w = 0.f;
    #pragma unroll
    for (int m = 0; m < 16; ++m) {
        const float2 v = M[m][l];
        w += Cre[k * 16 + m] * v.x - Cim[k * 16 + m] * v.y;
    }
    if (i == j) w += Dm[t];
    const unsigned short h = f2bf_rne(w);
    Wh[widx] = h;
    Wl[widx] = f2bf_rne(w - bf2f(h));
}

// -------- main GEMM: fused A-convert, 2-term, dbuf LDS, 1 barrier/chunk -----
__global__ __launch_bounds__(256) void gemm_fused_kernel(
    const float* __restrict__ X,
    const unsigned short* __restrict__ Wh, const unsigned short* __restrict__ Wl,
    float* __restrict__ Y)
{
    // buf layout (ushorts): [0,4096) A-tile, [4096,8192) Wh, [8192,12288) Wl
    __shared__ alignas(16) unsigned short s_lds[2][3 * 4096];  // 48 KB

    const int bid = blockIdx.x;
    const int nb = bid & 7;            // N-tile; mt-major => same-mt co-resident
    const int mt = bid >> 3;
    const int t = threadIdx.x;
    const int wid = t >> 6, lane = t & 63;
    const int wr = wid >> 1, wc = wid & 1;
    const int l15 = lane & 15, lg = lane >> 4;
    const int nk = (nb + 1) * 4;       // triangular K-limit (chunks of 32)

    f32x4 acc[4][4] = {};

    // X slots this thread owns: s = t and t+256; row = s>>2, g8 = s&3
    const int row0 = t >> 2, g8 = t & 3;

    float4 xr[2][2];
    auto x_issue = [&](int kc) {     // issue fp32 loads for chunk kc -> regs
        #pragma unroll
        for (int h = 0; h < 2; ++h) {
            const float* src = X + (size_t)(mt * 128 + h * 64 + row0) * 1024
                             + kc * 32 + g8 * 8;
            xr[h][0] = *reinterpret_cast<const float4*>(src);
            xr[h][1] = *reinterpret_cast<const float4*>(src + 4);
        }
    };
    auto w_issue = [&](unsigned short* buf, int kc) {  // gld_lds Wh/Wl
        const size_t wb = ((size_t)(nb * 32 + kc)) << 12;
        #pragma unroll
        for (int p = 0; p < 4; ++p) {
            const int e8 = (((p & 1) << 8) + t) * 8;
            const unsigned short* src = (p < 2) ? (Wh + wb + e8) : (Wl + wb + e8);
            gld_lds16(src, buf + 4096 + ((p >> 1) << 12) + e8);
        }
    };
    auto x_write = [&](unsigned short* buf) {          // cvt + ds_write_b128
        #pragma unroll
        for (int h = 0; h < 2; ++h) {
            short8v hv;
            const float* f = reinterpret_cast<const float*>(&xr[h][0]);
            #pragma unroll
            for (int e = 0; e < 8; ++e) hv[e] = (short)f2bf_rne(f[e]);
            *reinterpret_cast<short8v*>(
                buf + (g8 << 10) + ((h * 64 + row0) << 3)) = hv;
        }
    };

    // prologue: fill buf0 for kc=0
    x_issue(0);
    w_issue(s_lds[0], 0);
    x_write(s_lds[0]);
    __syncthreads();                   // drains vm+lgkm: buf0 ready

    int cur = 0;
    for (int kc = 0; kc < nk; ++kc) {
        const bool more = (kc + 1 < nk);
        if (more) {
            x_issue(kc + 1);                 // fp32 loads early (latency hidden)
            w_issue(s_lds[cur ^ 1], kc + 1); // gld_lds in flight across MFMA
        }

        const unsigned short* xh = s_lds[cur];
        const unsigned short* wh = xh + 4096;
        const unsigned short* wl = xh + 8192;

        short8v ah[4], bh[4], bl[4];
        #pragma unroll
        for (int mm = 0; mm < 4; ++mm) {
            const int o = (lg << 10) + ((wr * 64 + mm * 16 + l15) << 3);
            ah[mm] = *reinterpret_cast<const short8v*>(xh + o);
        }
        #pragma unroll
        for (int nn = 0; nn < 4; ++nn) {
            const int o = (lg << 10) + ((wc * 64 + nn * 16 + l15) << 3);
            bh[nn] = *reinterpret_cast<const short8v*>(wh + o);
            bl[nn] = *reinterpret_cast<const short8v*>(wl + o);
        }
        #pragma unroll
        for (int mm = 0; mm < 4; ++mm) {
            #pragma unroll
            for (int nn = 0; nn < 4; ++nn) {
                acc[mm][nn] = __builtin_amdgcn_mfma_f32_16x16x32_bf16(
                    ah[mm], bh[nn], acc[mm][nn], 0, 0, 0);
                acc[mm][nn] = __builtin_amdgcn_mfma_f32_16x16x32_bf16(
                    ah[mm], bl[nn], acc[mm][nn], 0, 0, 0);
            }
        }

        if (more) x_write(s_lds[cur ^ 1]);  // next A into next buf (safe: last
                                            // read of that buf ended at kc-1)
        __syncthreads();   // all waves done reading cur; next buf fully landed
        cur ^= 1;
    }

    // ---- epilogue: C/D layout col=lane&15, row=(lane>>4)*4+q ----
    #pragma unroll
    for (int mm = 0; mm < 4; ++mm) {
        const int grow = mt * 128 + wr * 64 + mm * 16 + lg * 4;
        #pragma unroll
        for (int nn = 0; nn < 4; ++nn) {
            const int gcol = nb * 128 + wc * 64 + nn * 16 + l15;
            #pragma unroll
            for (int q = 0; q < 4; ++q)
                Y[(size_t)(grow + q) * 1024 + gcol] = acc[mm][nn][q];
        }
    }
}

} // namespace

extern "C" void kernel_launch(void* const* d_in, const int* in_sizes, int n_in,
                              void* d_out, int out_size, void* d_ws, size_t ws_size,
                              hipStream_t stream) {
    const float* x   = (const float*)d_in[0];
    const float* Lre = (const float*)d_in[1];
    const float* Lim = (const float*)d_in[2];
    const float* Bre = (const float*)d_in[3];
    const float* Bim = (const float*)d_in[4];
    const float* Cre = (const float*)d_in[5];
    const float* Cim = (const float*)d_in[6];
    const float* Dm  = (const float*)d_in[7];
    float* y = (float*)d_out;

    const int positions = in_sizes[0] / 1024;          // 32768
    const int mtiles = positions / 128;                // 256

    unsigned short* Wh = (unsigned short*)d_ws;        // 2 MB
    unsigned short* Wl = Wh + 1024 * 1024;             // 2 MB

    build_w_kernel<<<64 * 64, 256, 0, stream>>>(Lre, Lim, Bre, Bim, Cre, Cim, Dm, Wh, Wl);
    gemm_fused_kernel<<<mtiles * 8, 256, 0, stream>>>(x, Wh, Wl, y);
}

// Round 6
// 157.654 us; speedup vs baseline: 1.2670x; 1.2670x over previous
//
#include <hip/hip_runtime.h>

// ImageLRU as one GEMM: y[r,:] = W @ x[r,:], W (1024x1024, block-lower-tri)
// built on device. R6: deep-pipelined GEMM (T3+T4+T5):
//   BM=256 x BN=128, BK=32, 512 thr (8 waves, 4Mx2N), 4-buffer LDS (128 KB),
//   depth-3 prefetch with counted s_waitcnt vmcnt(12/8/4/0) -- never drained
//   mid-loop -- raw s_barrier pairs, setprio around the MFMA cluster.
// 2-term precision: y = Xh*(Wh+Wl). Operand ws layouts == exact LDS images
// (linear global_load_lds, kg-major subtiles, measured conflict-free in R4).

namespace {

typedef __attribute__((ext_vector_type(8))) short short8v;
typedef __attribute__((ext_vector_type(4))) float f32x4;

__device__ inline unsigned short f2bf_rne(float f) {
    unsigned u = __builtin_bit_cast(unsigned, f);
    u += 0x7fffu + ((u >> 16) & 1u);
    return (unsigned short)(u >> 16);
}
__device__ inline float bf2f(unsigned short h) {
    unsigned u = ((unsigned)h) << 16;
    return __builtin_bit_cast(float, u);
}

__device__ inline void gld_lds16(const unsigned short* g, unsigned short* l) {
    __builtin_amdgcn_global_load_lds(
        (const __attribute__((address_space(1))) unsigned int*)g,
        (__attribute__((address_space(3))) unsigned int*)l, 16, 0, 0);
}

// W tile (128 n-rows x 32 k) = 4096 ushorts at base (nb*32+kc)<<12:
//   elem(row,k) at base + ((k>>3)<<10) + (row<<3) + (k&7)
// A tile (256 m-rows x 32 k) = 8192 ushorts at base (mt*32+kc)<<13:
//   elem(row,k) at base + ((k>>3)<<11) + (row<<3) + (k&7)

// ---------------- prep: build Wh/Wl (tiled layout, unchanged math) ----------
__global__ __launch_bounds__(256) void build_w_kernel(
    const float* __restrict__ Lre, const float* __restrict__ Lim,
    const float* __restrict__ Bre, const float* __restrict__ Bim,
    const float* __restrict__ Cre, const float* __restrict__ Cim,
    const float* __restrict__ Dm,
    unsigned short* __restrict__ Wh, unsigned short* __restrict__ Wl)
{
    const int i = blockIdx.x >> 6, j = blockIdx.x & 63;
    const int t = threadIdx.x, k = t >> 4, l = t & 15;

    const int n_g = i * 16 + k;        // W row (n dim)
    const int k_g = j * 16 + l;        // W col (k dim)
    const size_t widx = (((size_t)((n_g >> 7) * 32 + (k_g >> 5))) << 12)
                      + (((k_g >> 3) & 3) << 10) + ((n_g & 127) << 3) + (k_g & 7);

    if (j > i) { Wh[widx] = 0; Wl[widx] = 0; return; }

    __shared__ float2 Bs[16][16];
    __shared__ float2 M[16][16];
    Bs[k][l] = make_float2(Bre[t], Bim[t]);
    M[k][l]  = make_float2(k == l ? 1.f : 0.f, 0.f);
    const int delta = i - j;
    __syncthreads();

    #pragma unroll
    for (int d = 0; d < 6; ++d) {
        const int s = 1 << d;
        if (delta & s) {
            const float lr = Lre[k], li = Lim[k];
            const float2 m0 = M[k][l];
            M[k][l] = make_float2(lr * m0.x - li * m0.y, lr * m0.y + li * m0.x);
            __syncthreads();
        } else if (j + (delta & (s - 1)) >= s) {
            float2 acc = make_float2(0.f, 0.f);
            #pragma unroll
            for (int m = 0; m < 16; ++m) {
                const float2 b = Bs[k][m], v = M[m][l];
                acc.x += b.x * v.x - b.y * v.y;
                acc.y += b.x * v.y + b.y * v.x;
            }
            __syncthreads();
            M[k][l] = acc;
            __syncthreads();
        }
    }

    float w = 0.f;
    #pragma unroll
    for (int m = 0; m < 16; ++m) {
        const float2 v = M[m][l];
        w += Cre[k * 16 + m] * v.x - Cim[k * 16 + m] * v.y;
    }
    if (i == j) w += Dm[t];
    const unsigned short h = f2bf_rne(w);
    Wh[widx] = h;
    Wl[widx] = f2bf_rne(w - bf2f(h));
}

// ---------------- prep: X -> Xh bf16 (256-row A-tile layout) ----------------
__global__ __launch_bounds__(512) void split_x_kernel(
    const float* __restrict__ X, unsigned short* __restrict__ Xh)
{
    const int mt = blockIdx.x >> 5;    // 256-row tile (0..127)
    const int kc = blockIdx.x & 31;    // 32-col chunk
    const int t = threadIdx.x;
    const size_t base = ((size_t)(mt * 32 + kc)) << 13;

    #pragma unroll
    for (int p = 0; p < 2; ++p) {
        const int s = p * 512 + t;     // 16B slot id in [0,1024)
        const int kg = s >> 8, row = s & 255;
        const float* src = X + (size_t)(mt * 256 + row) * 1024 + kc * 32 + kg * 8;
        const float4 a = *reinterpret_cast<const float4*>(src);
        const float4 b = *reinterpret_cast<const float4*>(src + 4);
        short8v hv;
        hv[0] = (short)f2bf_rne(a.x); hv[1] = (short)f2bf_rne(a.y);
        hv[2] = (short)f2bf_rne(a.z); hv[3] = (short)f2bf_rne(a.w);
        hv[4] = (short)f2bf_rne(b.x); hv[5] = (short)f2bf_rne(b.y);
        hv[6] = (short)f2bf_rne(b.z); hv[7] = (short)f2bf_rne(b.w);
        *reinterpret_cast<short8v*>(Xh + base + (size_t)s * 8) = hv;  // coalesced 16B
    }
}

// ------------- main GEMM: 256x128, depth-3 counted-vmcnt pipeline -----------
__global__ __launch_bounds__(512) void gemm_tiled_kernel(
    const unsigned short* __restrict__ Xh,
    const unsigned short* __restrict__ Wh, const unsigned short* __restrict__ Wl,
    float* __restrict__ Y)
{
    // per buffer (ushorts): A [0,8192), Wh [8192,12288), Wl [12288,16384)
    __shared__ alignas(16) unsigned short s_lds[4][16384];   // 128 KB

    const int bid = blockIdx.x;
    const int nb = 7 - (bid >> 7);     // heavy N-tiles first (LPT)
    const int mt = bid & 127;
    const int t = threadIdx.x;
    const int wid = t >> 6, lane = t & 63;
    const int wr = wid >> 1, wc = wid & 1;     // 4Mx2N wave grid
    const int l15 = lane & 15, lg = lane >> 4;
    const int nk = (nb + 1) * 4;       // triangular K-limit (chunks of 32)

    f32x4 acc[4][4] = {};

    auto stage = [&](int kc) {         // 4 gld_lds16 per thread
        unsigned short* buf = s_lds[kc & 3];
        const size_t ab = ((size_t)(mt * 32 + kc)) << 13;
        const size_t wb = ((size_t)(nb * 32 + kc)) << 12;
        gld_lds16(Xh + ab + t * 8,        buf + t * 8);
        gld_lds16(Xh + ab + 4096 + t * 8, buf + 4096 + t * 8);
        gld_lds16(Wh + wb + t * 8,        buf + 8192 + t * 8);
        gld_lds16(Wl + wb + t * 8,        buf + 12288 + t * 8);
    };

    // prologue: 3 chunks in flight (nk >= 4 always)
    stage(0); stage(1); stage(2);

    for (int kc = 0; kc < nk; ++kc) {
        int inflight = nk - 1 - kc;
        if (inflight > 3) inflight = 3;
        if (inflight == 3) {
            stage(kc + 3);
            asm volatile("s_waitcnt vmcnt(12)" ::: "memory");
        } else if (inflight == 2) {
            asm volatile("s_waitcnt vmcnt(8)" ::: "memory");
        } else if (inflight == 1) {
            asm volatile("s_waitcnt vmcnt(4)" ::: "memory");
        } else {
            asm volatile("s_waitcnt vmcnt(0)" ::: "memory");
        }
        __builtin_amdgcn_s_barrier();          // buf[kc&3] fully landed (all waves)
        __builtin_amdgcn_sched_barrier(0);     // no ds_read hoists above barrier

        const unsigned short* buf = s_lds[kc & 3];
        short8v ah[4], bh[4], bl[4];
        #pragma unroll
        for (int mm = 0; mm < 4; ++mm)
            ah[mm] = *reinterpret_cast<const short8v*>(
                buf + (lg << 11) + ((wr * 64 + mm * 16 + l15) << 3));
        #pragma unroll
        for (int nn = 0; nn < 4; ++nn) {
            const int o = (lg << 10) + ((wc * 64 + nn * 16 + l15) << 3);
            bh[nn] = *reinterpret_cast<const short8v*>(buf + 8192 + o);
            bl[nn] = *reinterpret_cast<const short8v*>(buf + 12288 + o);
        }

        __builtin_amdgcn_s_setprio(1);
        #pragma unroll
        for (int mm = 0; mm < 4; ++mm) {
            #pragma unroll
            for (int nn = 0; nn < 4; ++nn) {
                acc[mm][nn] = __builtin_amdgcn_mfma_f32_16x16x32_bf16(
                    ah[mm], bh[nn], acc[mm][nn], 0, 0, 0);
                acc[mm][nn] = __builtin_amdgcn_mfma_f32_16x16x32_bf16(
                    ah[mm], bl[nn], acc[mm][nn], 0, 0, 0);
            }
        }
        __builtin_amdgcn_s_setprio(0);
        __builtin_amdgcn_sched_barrier(0);
        __builtin_amdgcn_s_barrier();          // all reads of buf[kc&3] retired
        __builtin_amdgcn_sched_barrier(0);     // no next-stage DMA hoists above
    }

    // ---- epilogue: C/D layout col=lane&15, row=(lane>>4)*4+q ----
    #pragma unroll
    for (int mm = 0; mm < 4; ++mm) {
        const int grow = mt * 256 + wr * 64 + mm * 16 + lg * 4;
        #pragma unroll
        for (int nn = 0; nn < 4; ++nn) {
            const int gcol = nb * 128 + wc * 64 + nn * 16 + l15;
            #pragma unroll
            for (int q = 0; q < 4; ++q)
                Y[(size_t)(grow + q) * 1024 + gcol] = acc[mm][nn][q];
        }
    }
}

} // namespace

extern "C" void kernel_launch(void* const* d_in, const int* in_sizes, int n_in,
                              void* d_out, int out_size, void* d_ws, size_t ws_size,
                              hipStream_t stream) {
    const float* x   = (const float*)d_in[0];
    const float* Lre = (const float*)d_in[1];
    const float* Lim = (const float*)d_in[2];
    const float* Bre = (const float*)d_in[3];
    const float* Bim = (const float*)d_in[4];
    const float* Cre = (const float*)d_in[5];
    const float* Cim = (const float*)d_in[6];
    const float* Dm  = (const float*)d_in[7];
    float* y = (float*)d_out;

    const int positions = in_sizes[0] / 1024;          // 32768
    const int mtiles = positions / 256;                // 128

    unsigned short* Wh = (unsigned short*)d_ws;        // 2 MB
    unsigned short* Wl = Wh + 1024 * 1024;             // 2 MB
    unsigned short* Xh = Wl + 1024 * 1024;             // 64 MB

    build_w_kernel<<<64 * 64, 256, 0, stream>>>(Lre, Lim, Bre, Bim, Cre, Cim, Dm, Wh, Wl);
    split_x_kernel<<<mtiles * 32, 512, 0, stream>>>(x, Xh);
    gemm_tiled_kernel<<<mtiles * 8, 512, 0, stream>>>(Xh, Wh, Wl, y);
}

// Round 7
// 121.577 us; speedup vs baseline: 1.6429x; 1.2967x over previous
//
#include <hip/hip_runtime.h>

// ImageLRU as one GEMM: y[r,:] = W @ x[r,:], W (1024x1024, block-lower-tri)
// built on device. R7 = R4 structure (proven 966 TF eff) with 1-TERM precision:
//   y = bf16(X) * bf16(W)   (error ~ sqrt(2) x the 2-term scheme, both X- and
//   W-rounding random-walk over K; predicted absmax ~12-16k < 32768 threshold)
// -> halves MFMA work, cuts staged bytes 1/3, LDS dbuf 48->32 KB (5 blocks/CU).
// build_w + split_x merged into one prep kernel (fewer launch gaps).

namespace {

typedef __attribute__((ext_vector_type(8))) short short8v;
typedef __attribute__((ext_vector_type(4))) float f32x4;

__device__ inline unsigned short f2bf_rne(float f) {
    unsigned u = __builtin_bit_cast(unsigned, f);
    u += 0x7fffu + ((u >> 16) & 1u);
    return (unsigned short)(u >> 16);
}

__device__ inline void gld_lds16(const unsigned short* g, unsigned short* l) {
    __builtin_amdgcn_global_load_lds(
        (const __attribute__((address_space(1))) unsigned int*)g,
        (__attribute__((address_space(3))) unsigned int*)l, 16, 0, 0);
}

// Tiled layout for a [128 rows][32 k] bf16 tile: elem (row,k) at
//   tile_base + ((k>>3)<<10) + (row<<3) + (k&7)   (ushort units, 4096/tile)
// == exact LDS image (linear global_load_lds, conflict-free ds_read_b128).

// ------------- prep: blocks [0,4096) build W; [4096,12288) split X ----------
__global__ __launch_bounds__(256) void prep_kernel(
    const float* __restrict__ X,
    const float* __restrict__ Lre, const float* __restrict__ Lim,
    const float* __restrict__ Bre, const float* __restrict__ Bim,
    const float* __restrict__ Cre, const float* __restrict__ Cim,
    const float* __restrict__ Dm,
    unsigned short* __restrict__ Wh, unsigned short* __restrict__ Xh)
{
    const int t = threadIdx.x;

    if (blockIdx.x < 4096) {
        // ---- build W block (i,j): T = prod of stage factors; W = Re(C*T)+D ----
        const int i = blockIdx.x >> 6, j = blockIdx.x & 63;
        const int k = t >> 4, l = t & 15;

        const int n_g = i * 16 + k;        // W row (n dim)
        const int k_g = j * 16 + l;        // W col (k dim)
        const size_t widx = (((size_t)((n_g >> 7) * 32 + (k_g >> 5))) << 12)
                          + (((k_g >> 3) & 3) << 10) + ((n_g & 127) << 3) + (k_g & 7);

        if (j > i) { Wh[widx] = 0; return; }

        __shared__ float2 Bs[16][16];
        __shared__ float2 M[16][16];
        Bs[k][l] = make_float2(Bre[t], Bim[t]);
        M[k][l]  = make_float2(k == l ? 1.f : 0.f, 0.f);
        const int delta = i - j;
        __syncthreads();

        #pragma unroll
        for (int d = 0; d < 6; ++d) {
            const int s = 1 << d;
            if (delta & s) {
                const float lr = Lre[k], li = Lim[k];
                const float2 m0 = M[k][l];
                M[k][l] = make_float2(lr * m0.x - li * m0.y, lr * m0.y + li * m0.x);
                __syncthreads();
            } else if (j + (delta & (s - 1)) >= s) {
                float2 acc = make_float2(0.f, 0.f);
                #pragma unroll
                for (int m = 0; m < 16; ++m) {
                    const float2 b = Bs[k][m], v = M[m][l];
                    acc.x += b.x * v.x - b.y * v.y;
                    acc.y += b.x * v.y + b.y * v.x;
                }
                __syncthreads();
                M[k][l] = acc;
                __syncthreads();
            }
        }

        float w = 0.f;
        #pragma unroll
        for (int m = 0; m < 16; ++m) {
            const float2 v = M[m][l];
            w += Cre[k * 16 + m] * v.x - Cim[k * 16 + m] * v.y;
        }
        if (i == j) w += Dm[t];
        Wh[widx] = f2bf_rne(w);
    } else {
        // ---- split X tile (mt, kc) -> bf16 tiled layout ----
        const int sid = blockIdx.x - 4096;
        const int mt = sid >> 5;           // 128-row tile (0..255)
        const int kc = sid & 31;           // 32-col chunk
        const size_t tb = ((size_t)(mt * 32 + kc)) << 12;

        #pragma unroll
        for (int p = 0; p < 4; ++p) {
            const int f = p * 256 + t;          // float4 id in [0,1024)
            const int row = f >> 3, c4 = f & 7;
            const float4 v = *reinterpret_cast<const float4*>(
                X + (size_t)(mt * 128 + row) * 1024 + kc * 32 + c4 * 4);
            ushort4 hv;
            hv.x = f2bf_rne(v.x);
            hv.y = f2bf_rne(v.y);
            hv.z = f2bf_rne(v.z);
            hv.w = f2bf_rne(v.w);
            const size_t o = tb + ((size_t)(c4 >> 1) << 10) + (row << 3) + ((c4 & 1) << 2);
            *reinterpret_cast<ushort4*>(Xh + o) = hv;
        }
    }
}

// -------- main GEMM: 1-term, dbuf LDS (32 KB), 1 barrier / K-chunk ----------
__global__ __launch_bounds__(256) void gemm_tiled_kernel(
    const unsigned short* __restrict__ Xh,
    const unsigned short* __restrict__ Wh,
    float* __restrict__ Y, int mtiles)
{
    // per buffer (ushorts): [0,4096) A-tile, [4096,8192) W-tile
    __shared__ alignas(16) unsigned short s_lds[2][2 * 4096];  // 32 KB

    const int bid = blockIdx.x;
    const int nb = 7 - bid / mtiles;   // heavy N-tiles first (LPT)
    const int mt = bid % mtiles;
    const int t = threadIdx.x;
    const int wid = t >> 6, lane = t & 63;
    const int wr = wid >> 1, wc = wid & 1;
    const int l15 = lane & 15, lg = lane >> 4;
    const int nk = (nb + 1) * 4;       // triangular K-limit (chunks of 32)

    f32x4 acc[4][4] = {};

    auto stage = [&](unsigned short* buf, int kc) {
        const size_t xb = ((size_t)(mt * 32 + kc)) << 12;
        const size_t wb = ((size_t)(nb * 32 + kc)) << 12;
        #pragma unroll
        for (int p = 0; p < 4; ++p) {
            const int e8 = (((p & 1) << 8) + t) * 8;   // ushort offset of 16B slot
            const unsigned short* src = (p < 2) ? (Xh + xb + e8) : (Wh + wb + e8);
            gld_lds16(src, buf + ((p >> 1) << 12) + e8);
        }
    };

    stage(s_lds[0], 0);
    __syncthreads();                    // drains vmcnt(0): buf0 ready

    int cur = 0;
    for (int kc = 0; kc < nk; ++kc) {
        if (kc + 1 < nk) stage(s_lds[cur ^ 1], kc + 1);  // overlap with MFMA below

        const unsigned short* xh = s_lds[cur];
        const unsigned short* wh = xh + 4096;

        short8v ah[4], bh[4];
        #pragma unroll
        for (int mm = 0; mm < 4; ++mm) {
            const int o = (lg << 10) + ((wr * 64 + mm * 16 + l15) << 3);
            ah[mm] = *reinterpret_cast<const short8v*>(xh + o);
        }
        #pragma unroll
        for (int nn = 0; nn < 4; ++nn) {
            const int o = (lg << 10) + ((wc * 64 + nn * 16 + l15) << 3);
            bh[nn] = *reinterpret_cast<const short8v*>(wh + o);
        }
        #pragma unroll
        for (int mm = 0; mm < 4; ++mm) {
            #pragma unroll
            for (int nn = 0; nn < 4; ++nn) {
                acc[mm][nn] = __builtin_amdgcn_mfma_f32_16x16x32_bf16(
                    ah[mm], bh[nn], acc[mm][nn], 0, 0, 0);
            }
        }
        __syncthreads();   // reads of cur done (all waves) + next buf landed
        cur ^= 1;
    }

    // ---- epilogue: C/D layout col=lane&15, row=(lane>>4)*4+q ----
    #pragma unroll
    for (int mm = 0; mm < 4; ++mm) {
        const int grow = mt * 128 + wr * 64 + mm * 16 + lg * 4;
        #pragma unroll
        for (int nn = 0; nn < 4; ++nn) {
            const int gcol = nb * 128 + wc * 64 + nn * 16 + l15;
            #pragma unroll
            for (int q = 0; q < 4; ++q)
                Y[(size_t)(grow + q) * 1024 + gcol] = acc[mm][nn][q];
        }
    }
}

} // namespace

extern "C" void kernel_launch(void* const* d_in, const int* in_sizes, int n_in,
                              void* d_out, int out_size, void* d_ws, size_t ws_size,
                              hipStream_t stream) {
    const float* x   = (const float*)d_in[0];
    const float* Lre = (const float*)d_in[1];
    const float* Lim = (const float*)d_in[2];
    const float* Bre = (const float*)d_in[3];
    const float* Bim = (const float*)d_in[4];
    const float* Cre = (const float*)d_in[5];
    const float* Cim = (const float*)d_in[6];
    const float* Dm  = (const float*)d_in[7];
    float* y = (float*)d_out;

    const int positions = in_sizes[0] / 1024;          // 32768
    const int mtiles = positions / 128;                // 256

    unsigned short* Wh = (unsigned short*)d_ws;        // 2 MB
    unsigned short* Xh = Wh + 1024 * 1024;             // 64 MB

    prep_kernel<<<4096 + mtiles * 32, 256, 0, stream>>>(
        x, Lre, Lim, Bre, Bim, Cre, Cim, Dm, Wh, Xh);
    gemm_tiled_kernel<<<mtiles * 8, 256, 0, stream>>>(Xh, Wh, y, mtiles);
}

// Round 8
// 121.338 us; speedup vs baseline: 1.6462x; 1.0020x over previous
//
#include <hip/hip_runtime.h>

// ImageLRU as one GEMM: y[r,:] = W @ x[r,:], W (1024x1024, block-lower-tri)
// built on device. R8 = R7 skeleton with W moved out of LDS:
//  - Wh (2 MB total) is L2-resident; B-fragments are loaded straight from
//    global into registers (coalesced 16B/lane), double-buffered one K-chunk
//    ahead with NAMED register sets (static indexing, kc-loop unrolled x2).
//  - LDS holds only the A tile (8 KB/buf, dbuf 16 KB) via global_load_lds.
//    -> ~5 blocks/CU occupancy, 1 barrier per K-chunk, conflict-free reads.
//  - 1-term precision: y = bf16(X) * bf16(W)  (absmax 8192, thr 32768).

namespace {

typedef __attribute__((ext_vector_type(8))) short short8v;
typedef __attribute__((ext_vector_type(4))) float f32x4;

__device__ inline unsigned short f2bf_rne(float f) {
    unsigned u = __builtin_bit_cast(unsigned, f);
    u += 0x7fffu + ((u >> 16) & 1u);
    return (unsigned short)(u >> 16);
}

__device__ inline void gld_lds16(const unsigned short* g, unsigned short* l) {
    __builtin_amdgcn_global_load_lds(
        (const __attribute__((address_space(1))) unsigned int*)g,
        (__attribute__((address_space(3))) unsigned int*)l, 16, 0, 0);
}

// Tiled layout for a [128 rows][32 k] bf16 tile: elem (row,k) at
//   tile_base + ((k>>3)<<10) + (row<<3) + (k&7)   (ushort units, 4096/tile)
// == exact LDS / fragment image (linear gld_lds, conflict-free ds_read_b128,
//    and for W: 16 consecutive lanes hit 256 contiguous bytes in L2).

// ------------- prep: blocks [0,4096) build W; [4096,12288) split X ----------
__global__ __launch_bounds__(256) void prep_kernel(
    const float* __restrict__ X,
    const float* __restrict__ Lre, const float* __restrict__ Lim,
    const float* __restrict__ Bre, const float* __restrict__ Bim,
    const float* __restrict__ Cre, const float* __restrict__ Cim,
    const float* __restrict__ Dm,
    unsigned short* __restrict__ Wh, unsigned short* __restrict__ Xh)
{
    const int t = threadIdx.x;

    if (blockIdx.x < 4096) {
        // ---- build W block (i,j): T = prod of stage factors; W = Re(C*T)+D ----
        const int i = blockIdx.x >> 6, j = blockIdx.x & 63;
        const int k = t >> 4, l = t & 15;

        const int n_g = i * 16 + k;        // W row (n dim)
        const int k_g = j * 16 + l;        // W col (k dim)
        const size_t widx = (((size_t)((n_g >> 7) * 32 + (k_g >> 5))) << 12)
                          + (((k_g >> 3) & 3) << 10) + ((n_g & 127) << 3) + (k_g & 7);

        if (j > i) { Wh[widx] = 0; return; }

        __shared__ float2 Bs[16][16];
        __shared__ float2 M[16][16];
        Bs[k][l] = make_float2(Bre[t], Bim[t]);
        M[k][l]  = make_float2(k == l ? 1.f : 0.f, 0.f);
        const int delta = i - j;
        __syncthreads();

        #pragma unroll
        for (int d = 0; d < 6; ++d) {
            const int s = 1 << d;
            if (delta & s) {
                const float lr = Lre[k], li = Lim[k];
                const float2 m0 = M[k][l];
                M[k][l] = make_float2(lr * m0.x - li * m0.y, lr * m0.y + li * m0.x);
                __syncthreads();
            } else if (j + (delta & (s - 1)) >= s) {
                float2 acc = make_float2(0.f, 0.f);
                #pragma unroll
                for (int m = 0; m < 16; ++m) {
                    const float2 b = Bs[k][m], v = M[m][l];
                    acc.x += b.x * v.x - b.y * v.y;
                    acc.y += b.x * v.y + b.y * v.x;
                }
                __syncthreads();
                M[k][l] = acc;
                __syncthreads();
            }
        }

        float w = 0.f;
        #pragma unroll
        for (int m = 0; m < 16; ++m) {
            const float2 v = M[m][l];
            w += Cre[k * 16 + m] * v.x - Cim[k * 16 + m] * v.y;
        }
        if (i == j) w += Dm[t];
        Wh[widx] = f2bf_rne(w);
    } else {
        // ---- split X tile (mt, kc) -> bf16 tiled layout ----
        const int sid = blockIdx.x - 4096;
        const int mt = sid >> 5;           // 128-row tile (0..255)
        const int kc = sid & 31;           // 32-col chunk
        const size_t tb = ((size_t)(mt * 32 + kc)) << 12;

        #pragma unroll
        for (int p = 0; p < 4; ++p) {
            const int f = p * 256 + t;          // float4 id in [0,1024)
            const int row = f >> 3, c4 = f & 7;
            const float4 v = *reinterpret_cast<const float4*>(
                X + (size_t)(mt * 128 + row) * 1024 + kc * 32 + c4 * 4);
            ushort4 hv;
            hv.x = f2bf_rne(v.x);
            hv.y = f2bf_rne(v.y);
            hv.z = f2bf_rne(v.z);
            hv.w = f2bf_rne(v.w);
            const size_t o = tb + ((size_t)(c4 >> 1) << 10) + (row << 3) + ((c4 & 1) << 2);
            *reinterpret_cast<ushort4*>(Xh + o) = hv;
        }
    }
}

// ------ main GEMM: A in LDS (dbuf 16 KB), W frags direct from L2 ------------
__global__ __launch_bounds__(256) void gemm_tiled_kernel(
    const unsigned short* __restrict__ Xh,
    const unsigned short* __restrict__ Wh,
    float* __restrict__ Y, int mtiles)
{
    __shared__ alignas(16) unsigned short s_lds[2][4096];  // A tiles, 16 KB

    const int bid = blockIdx.x;
    const int nb = 7 - bid / mtiles;   // heavy N-tiles first (LPT)
    const int mt = bid % mtiles;
    const int t = threadIdx.x;
    const int wid = t >> 6, lane = t & 63;
    const int wr = wid >> 1, wc = wid & 1;
    const int l15 = lane & 15, lg = lane >> 4;
    const int nk = (nb + 1) * 4;       // triangular K-limit (chunks of 32), even

    f32x4 acc[4][4] = {};

    // B-fragment global offsets (ushorts) within a W K-tile
    int wfo[4];
    #pragma unroll
    for (int nn = 0; nn < 4; ++nn)
        wfo[nn] = (lg << 10) + ((wc * 64 + nn * 16 + l15) << 3);

    auto stageA = [&](unsigned short* buf, int kc) {   // 2 gld_lds16 / thread
        const size_t xb = ((size_t)(mt * 32 + kc)) << 12;
        gld_lds16(Xh + xb + t * 8,        buf + t * 8);
        gld_lds16(Xh + xb + 2048 + t * 8, buf + 2048 + t * 8);
    };

    short8v bh0[4], bh1[4];
    auto loadW0 = [&](int kc) {
        const size_t wb = ((size_t)(nb * 32 + kc)) << 12;
        #pragma unroll
        for (int nn = 0; nn < 4; ++nn)
            bh0[nn] = *reinterpret_cast<const short8v*>(Wh + wb + wfo[nn]);
    };
    auto loadW1 = [&](int kc) {
        const size_t wb = ((size_t)(nb * 32 + kc)) << 12;
        #pragma unroll
        for (int nn = 0; nn < 4; ++nn)
            bh1[nn] = *reinterpret_cast<const short8v*>(Wh + wb + wfo[nn]);
    };

    auto computeA = [&](const unsigned short* buf, const short8v* bh) {
        short8v ah[4];
        #pragma unroll
        for (int mm = 0; mm < 4; ++mm) {
            const int o = (lg << 10) + ((wr * 64 + mm * 16 + l15) << 3);
            ah[mm] = *reinterpret_cast<const short8v*>(buf + o);
        }
        #pragma unroll
        for (int mm = 0; mm < 4; ++mm) {
            #pragma unroll
            for (int nn = 0; nn < 4; ++nn) {
                acc[mm][nn] = __builtin_amdgcn_mfma_f32_16x16x32_bf16(
                    ah[mm], bh[nn], acc[mm][nn], 0, 0, 0);
            }
        }
    };

    // prologue: chunk 0 in flight
    stageA(s_lds[0], 0);
    loadW0(0);
    __syncthreads();                   // vmcnt(0): buf0 + bh0 ready

    for (int kc = 0; kc < nk; kc += 2) {
        // even phase: compute (buf0, bh0); prefetch kc+1 (always < nk)
        stageA(s_lds[1], kc + 1);
        loadW1(kc + 1);
        computeA(s_lds[0], bh0);
        __syncthreads();               // buf0 reads done; buf1+bh1 landed

        // odd phase: compute (buf1, bh1); prefetch kc+2 if any
        if (kc + 2 < nk) {
            stageA(s_lds[0], kc + 2);
            loadW0(kc + 2);
        }
        computeA(s_lds[1], bh1);
        __syncthreads();               // buf1 reads done; buf0+bh0 landed
    }

    // ---- epilogue: C/D layout col=lane&15, row=(lane>>4)*4+q ----
    #pragma unroll
    for (int mm = 0; mm < 4; ++mm) {
        const int grow = mt * 128 + wr * 64 + mm * 16 + lg * 4;
        #pragma unroll
        for (int nn = 0; nn < 4; ++nn) {
            const int gcol = nb * 128 + wc * 64 + nn * 16 + l15;
            #pragma unroll
            for (int q = 0; q < 4; ++q)
                Y[(size_t)(grow + q) * 1024 + gcol] = acc[mm][nn][q];
        }
    }
}

} // namespace

extern "C" void kernel_launch(void* const* d_in, const int* in_sizes, int n_in,
                              void* d_out, int out_size, void* d_ws, size_t ws_size,
                              hipStream_t stream) {
    const float* x   = (const float*)d_in[0];
    const float* Lre = (const float*)d_in[1];
    const float* Lim = (const float*)d_in[2];
    const float* Bre = (const float*)d_in[3];
    const float* Bim = (const float*)d_in[4];
    const float* Cre = (const float*)d_in[5];
    const float* Cim = (const float*)d_in[6];
    const float* Dm  = (const float*)d_in[7];
    float* y = (float*)d_out;

    const int positions = in_sizes[0] / 1024;          // 32768
    const int mtiles = positions / 128;                // 256

    unsigned short* Wh = (unsigned short*)d_ws;        // 2 MB
    unsigned short* Xh = Wh + 1024 * 1024;             // 64 MB

    prep_kernel<<<4096 + mtiles * 32, 256, 0, stream>>>(
        x, Lre, Lim, Bre, Bim, Cre, Cim, Dm, Wh, Xh);
    gemm_tiled_kernel<<<mtiles * 8, 256, 0, stream>>>(Xh, Wh, y, mtiles);
}

// Round 9
// 120.603 us; speedup vs baseline: 1.6562x; 1.0061x over previous
//
#include <hip/hip_runtime.h>

// ImageLRU as one GEMM: y[r,:] = W @ x[r,:], W (1024x1024, block-lower-tri)
// built on device. R9: GEMM with NO LDS and NO barriers:
//  - A-fragments and W-fragments loaded straight from global into registers
//    (tiled ws layout: 16 consecutive lanes read 256 contiguous bytes ->
//    fully coalesced; X-slab L3-resident across nb re-reads, W 2MB L2-resident).
//  - 2-deep software pipeline with NAMED register sets (static indexing),
//    kc-loop unrolled x2. Compiler emits counted vmcnt waits automatically.
//  - 1-term precision: y = bf16(X) * bf16(W)  (absmax 8192, thr 32768).

namespace {

typedef __attribute__((ext_vector_type(8))) short short8v;
typedef __attribute__((ext_vector_type(4))) float f32x4;

__device__ inline unsigned short f2bf_rne(float f) {
    unsigned u = __builtin_bit_cast(unsigned, f);
    u += 0x7fffu + ((u >> 16) & 1u);
    return (unsigned short)(u >> 16);
}

// Tiled layout for a [128 rows][32 k] bf16 tile: elem (row,k) at
//   tile_base + ((k>>3)<<10) + (row<<3) + (k&7)   (ushort units, 4096/tile)

// ------------- prep: blocks [0,4096) build W; [4096,12288) split X ----------
__global__ __launch_bounds__(256) void prep_kernel(
    const float* __restrict__ X,
    const float* __restrict__ Lre, const float* __restrict__ Lim,
    const float* __restrict__ Bre, const float* __restrict__ Bim,
    const float* __restrict__ Cre, const float* __restrict__ Cim,
    const float* __restrict__ Dm,
    unsigned short* __restrict__ Wh, unsigned short* __restrict__ Xh)
{
    const int t = threadIdx.x;

    if (blockIdx.x < 4096) {
        // ---- build W block (i,j): T = prod of stage factors; W = Re(C*T)+D ----
        const int i = blockIdx.x >> 6, j = blockIdx.x & 63;
        const int k = t >> 4, l = t & 15;

        const int n_g = i * 16 + k;        // W row (n dim)
        const int k_g = j * 16 + l;        // W col (k dim)
        const size_t widx = (((size_t)((n_g >> 7) * 32 + (k_g >> 5))) << 12)
                          + (((k_g >> 3) & 3) << 10) + ((n_g & 127) << 3) + (k_g & 7);

        if (j > i) { Wh[widx] = 0; return; }

        __shared__ float2 Bs[16][16];
        __shared__ float2 M[16][16];
        Bs[k][l] = make_float2(Bre[t], Bim[t]);
        M[k][l]  = make_float2(k == l ? 1.f : 0.f, 0.f);
        const int delta = i - j;
        __syncthreads();

        #pragma unroll
        for (int d = 0; d < 6; ++d) {
            const int s = 1 << d;
            if (delta & s) {
                const float lr = Lre[k], li = Lim[k];
                const float2 m0 = M[k][l];
                M[k][l] = make_float2(lr * m0.x - li * m0.y, lr * m0.y + li * m0.x);
                __syncthreads();
            } else if (j + (delta & (s - 1)) >= s) {
                float2 acc = make_float2(0.f, 0.f);
                #pragma unroll
                for (int m = 0; m < 16; ++m) {
                    const float2 b = Bs[k][m], v = M[m][l];
                    acc.x += b.x * v.x - b.y * v.y;
                    acc.y += b.x * v.y + b.y * v.x;
                }
                __syncthreads();
                M[k][l] = acc;
                __syncthreads();
            }
        }

        float w = 0.f;
        #pragma unroll
        for (int m = 0; m < 16; ++m) {
            const float2 v = M[m][l];
            w += Cre[k * 16 + m] * v.x - Cim[k * 16 + m] * v.y;
        }
        if (i == j) w += Dm[t];
        Wh[widx] = f2bf_rne(w);
    } else {
        // ---- split X tile (mt, kc) -> bf16 tiled layout ----
        const int sid = blockIdx.x - 4096;
        const int mt = sid >> 5;           // 128-row tile (0..255)
        const int kc = sid & 31;           // 32-col chunk
        const size_t tb = ((size_t)(mt * 32 + kc)) << 12;

        #pragma unroll
        for (int p = 0; p < 4; ++p) {
            const int f = p * 256 + t;          // float4 id in [0,1024)
            const int row = f >> 3, c4 = f & 7;
            const float4 v = *reinterpret_cast<const float4*>(
                X + (size_t)(mt * 128 + row) * 1024 + kc * 32 + c4 * 4);
            ushort4 hv;
            hv.x = f2bf_rne(v.x);
            hv.y = f2bf_rne(v.y);
            hv.z = f2bf_rne(v.z);
            hv.w = f2bf_rne(v.w);
            const size_t o = tb + ((size_t)(c4 >> 1) << 10) + (row << 3) + ((c4 & 1) << 2);
            *reinterpret_cast<ushort4*>(Xh + o) = hv;
        }
    }
}

// ------ main GEMM: pure register pipeline, no LDS, no barriers --------------
__global__ __launch_bounds__(256) void gemm_reg_kernel(
    const unsigned short* __restrict__ Xh,
    const unsigned short* __restrict__ Wh,
    float* __restrict__ Y, int mtiles)
{
    const int bid = blockIdx.x;
    const int nb = 7 - bid / mtiles;   // heavy N-tiles first (LPT)
    const int mt = bid % mtiles;
    const int t = threadIdx.x;
    const int wid = t >> 6, lane = t & 63;
    const int wr = wid >> 1, wc = wid & 1;
    const int l15 = lane & 15, lg = lane >> 4;
    const int nk = (nb + 1) * 4;       // triangular K-limit (chunks of 32), even

    f32x4 acc[4][4] = {};

    // fragment offsets (ushorts) within a K-chunk tile
    int afo[4], wfo[4];
    #pragma unroll
    for (int mm = 0; mm < 4; ++mm)
        afo[mm] = (lg << 10) + ((wr * 64 + mm * 16 + l15) << 3);
    #pragma unroll
    for (int nn = 0; nn < 4; ++nn)
        wfo[nn] = (lg << 10) + ((wc * 64 + nn * 16 + l15) << 3);

    short8v a0[4], b0[4], a1[4], b1[4];

    auto load0 = [&](int kc) {
        const size_t xb = ((size_t)(mt * 32 + kc)) << 12;
        const size_t wb = ((size_t)(nb * 32 + kc)) << 12;
        #pragma unroll
        for (int mm = 0; mm < 4; ++mm)
            a0[mm] = *reinterpret_cast<const short8v*>(Xh + xb + afo[mm]);
        #pragma unroll
        for (int nn = 0; nn < 4; ++nn)
            b0[nn] = *reinterpret_cast<const short8v*>(Wh + wb + wfo[nn]);
    };
    auto load1 = [&](int kc) {
        const size_t xb = ((size_t)(mt * 32 + kc)) << 12;
        const size_t wb = ((size_t)(nb * 32 + kc)) << 12;
        #pragma unroll
        for (int mm = 0; mm < 4; ++mm)
            a1[mm] = *reinterpret_cast<const short8v*>(Xh + xb + afo[mm]);
        #pragma unroll
        for (int nn = 0; nn < 4; ++nn)
            b1[nn] = *reinterpret_cast<const short8v*>(Wh + wb + wfo[nn]);
    };
    auto mfma0 = [&]() {
        #pragma unroll
        for (int mm = 0; mm < 4; ++mm)
            #pragma unroll
            for (int nn = 0; nn < 4; ++nn)
                acc[mm][nn] = __builtin_amdgcn_mfma_f32_16x16x32_bf16(
                    a0[mm], b0[nn], acc[mm][nn], 0, 0, 0);
    };
    auto mfma1 = [&]() {
        #pragma unroll
        for (int mm = 0; mm < 4; ++mm)
            #pragma unroll
            for (int nn = 0; nn < 4; ++nn)
                acc[mm][nn] = __builtin_amdgcn_mfma_f32_16x16x32_bf16(
                    a1[mm], b1[nn], acc[mm][nn], 0, 0, 0);
    };

    // 2-deep pipeline, x2 unrolled (nk is a multiple of 4)
    load0(0);
    load1(1);
    for (int kc = 0; kc < nk; kc += 2) {
        mfma0();                       // waits only on a0/b0 (counted vmcnt)
        if (kc + 2 < nk) load0(kc + 2);
        mfma1();
        if (kc + 3 < nk) load1(kc + 3);
    }

    // ---- epilogue: C/D layout col=lane&15, row=(lane>>4)*4+q ----
    #pragma unroll
    for (int mm = 0; mm < 4; ++mm) {
        const int grow = mt * 128 + wr * 64 + mm * 16 + lg * 4;
        #pragma unroll
        for (int nn = 0; nn < 4; ++nn) {
            const int gcol = nb * 128 + wc * 64 + nn * 16 + l15;
            #pragma unroll
            for (int q = 0; q < 4; ++q)
                Y[(size_t)(grow + q) * 1024 + gcol] = acc[mm][nn][q];
        }
    }
}

} // namespace

extern "C" void kernel_launch(void* const* d_in, const int* in_sizes, int n_in,
                              void* d_out, int out_size, void* d_ws, size_t ws_size,
                              hipStream_t stream) {
    const float* x   = (const float*)d_in[0];
    const float* Lre = (const float*)d_in[1];
    const float* Lim = (const float*)d_in[2];
    const float* Bre = (const float*)d_in[3];
    const float* Bim = (const float*)d_in[4];
    const float* Cre = (const float*)d_in[5];
    const float* Cim = (const float*)d_in[6];
    const float* Dm  = (const float*)d_in[7];
    float* y = (float*)d_out;

    const int positions = in_sizes[0] / 1024;          // 32768
    const int mtiles = positions / 128;                // 256

    unsigned short* Wh = (unsigned short*)d_ws;        // 2 MB
    unsigned short* Xh = Wh + 1024 * 1024;             // 64 MB

    prep_kernel<<<4096 + mtiles * 32, 256, 0, stream>>>(
        x, Lre, Lim, Bre, Bim, Cre, Cim, Dm, Wh, Xh);
    gemm_reg_kernel<<<mtiles * 8, 256, 0, stream>>>(Xh, Wh, y, mtiles);
}